// Round 8
// baseline (135.659 us; speedup 1.0000x reference)
//
#include <hip/hip_runtime.h>
#include <cfloat>
#include <cmath>

#define N_TOK (32*4096)                 // 131072 tokens
#define DIM   64
#define N_E   1024

typedef __attribute__((ext_vector_type(8))) _Float16 f16x8;
typedef __attribute__((ext_vector_type(4))) float    f32x4;
typedef unsigned int u32;

// ws layout (bytes)
#define WS_CN2    0u                    // 1024 f32 (-0.5*||e||^2)           (4 KB)
#define WS_CBF    4096u                 // fragment-ordered f16 (single plane, 128 KB)
#define WS_GIDX   135168u               // 131072 int winner ids             (512 KB)
#define WS_COUNTS 659456u               // 1024 u32
#define WS_SSEA   663552u               // 64 f32 partial SSE cells
#define WS_DONE   663808u               // 1 u32

// Codebook -> MFMA B-fragment order, f16 single plane:
//   cbF[ch*1024 + kf*512 + (q*16+n)*8 + j],  ch = 16-code chunk 0..63
__global__ __launch_bounds__(256) void prep_kernel(const float* __restrict__ cb,
        float* __restrict__ cn2, _Float16* __restrict__ cbF,
        unsigned* __restrict__ counts, float* __restrict__ ssea, unsigned* __restrict__ done) {
    const int t = threadIdx.x;
    const int k = blockIdx.x * 32 + (t >> 3);        // code 0..1023
    const int oct = t & 7;
    if (t < 32) counts[blockIdx.x * 32 + t] = 0u;
    if (blockIdx.x == 0 && t < 64) ssea[t] = 0.f;
    if (blockIdx.x == 0 && t == 0) *done = 0u;

    const float4 a = *(const float4*)(cb + (size_t)k * DIM + oct * 8);
    const float4 b = *(const float4*)(cb + (size_t)k * DIM + oct * 8 + 4);
    float v[8] = {a.x,a.y,a.z,a.w,b.x,b.y,b.z,b.w};
    f16x8 hv;
    float nrm = 0.f;
#pragma unroll
    for (int j = 0; j < 8; ++j) {
        float f = v[j];
        nrm = fmaf(f, f, nrm);
        hv[j] = (_Float16)f;
    }
    const int ch = k >> 4, n = k & 15;
    const int kf = oct >> 2, q = oct & 3;
    *(f16x8*)(cbF + (size_t)(ch * 1024 + kf * 512 + q * 128 + n * 8)) = hv;
    nrm += __shfl_xor(nrm, 1, 64);
    nrm += __shfl_xor(nrm, 2, 64);
    nrm += __shfl_xor(nrm, 4, 64);
    if (oct == 0) cn2[k] = -0.5f * nrm;              // exact fp32 -||e||^2/2
}

// Round-13 (= r12 retry; prior round failed on container infra, not kernel):
// register-streaming (no barriers, no LDS staging) at 4 blocks/CU: 1024
// blocks x 128 tokens, 32 tokens/wave (2 A-tiles). r6 post-mortem: ~68% idle
// cycles at 2 waves/SIMD and in-wave pipelining (depth-4) regressed, so the
// lever is TLP. Loop is the PROVEN depth-2 4-BSet structure (r3). Packed-
// score SSE (bit-identical r0/r2/r5), gidx publish + separate hist dispatch
// (r5 proved fused global hist atomics cost more than the hist dispatch).
struct BSet { f16x8 h0, h1; float cn; };

__device__ __forceinline__ BSet loadB(const _Float16* __restrict__ cbF,
                                      const float* __restrict__ cn2,
                                      int ch, int lane, int n) {
    const _Float16* p = cbF + (size_t)((ch << 10) + (lane << 3));
    BSet s;
    s.h0 = *(const f16x8*)(p);
    s.h1 = *(const f16x8*)(p + 512);
    s.cn = cn2[(ch << 4) | n];
    return s;
}

__global__ __launch_bounds__(256, 4) void fused_kernel(const float* __restrict__ z,
        const _Float16* __restrict__ cbF, const float* __restrict__ cn2,
        const float* __restrict__ cb, float* __restrict__ out,
        int* __restrict__ gidx, float* __restrict__ ssea) {
    __shared__ int lidx[128];                        // wave-local id bounce only
    const int t    = threadIdx.x;
    const int lane = t & 63;
    const int w    = t >> 6;
    const int n    = lane & 15;                      // MFMA col (code) / token row idx
    const int q    = lane >> 4;                      // k-octet selector
    const int wtok = blockIdx.x * 128 + w * 32;

    // A fragments (32 tokens/wave as 2 tiles x 2 K-halves), f16 in regs + norms.
    f16x8 ah[2][2];
    float pn[2];
    const float4* z4 = (const float4*)z;
#pragma unroll
    for (int tile = 0; tile < 2; ++tile) {
        int tok = wtok + tile*16 + n;
        float nrm = 0.f;
#pragma unroll
        for (int kf = 0; kf < 2; ++kf) {
            float4 p0 = z4[(size_t)tok*16 + kf*8 + q*2];
            float4 p1 = z4[(size_t)tok*16 + kf*8 + q*2 + 1];
            float v[8] = {p0.x,p0.y,p0.z,p0.w,p1.x,p1.y,p1.z,p1.w};
            f16x8 hv;
#pragma unroll
            for (int j = 0; j < 8; ++j) {
                float f = v[j];
                nrm = fmaf(f, f, nrm);
                hv[j] = (_Float16)f;
            }
            ah[tile][kf] = hv;
        }
        nrm += __shfl_xor(nrm, 16, 64);
        nrm += __shfl_xor(nrm, 32, 64);
        pn[tile] = nrm;
    }

    float best[8];
#pragma unroll
    for (int s = 0; s < 8; ++s) best[s] = -3.4e38f;

#define COMPUTE(S, CH) do {                                                       \
        const float cnv_ = (S).cn;                                               \
        const u32 codebits_ = (u32)(((CH) << 4) | n);                            \
        _Pragma("unroll")                                                        \
        for (int tile = 0; tile < 2; ++tile) {                                   \
            f32x4 acc = {cnv_, cnv_, cnv_, cnv_};                                \
            acc = __builtin_amdgcn_mfma_f32_16x16x32_f16(ah[tile][0], (S).h0, acc, 0, 0, 0); \
            acc = __builtin_amdgcn_mfma_f32_16x16x32_f16(ah[tile][1], (S).h1, acc, 0, 0, 0); \
            _Pragma("unroll")                                                    \
            for (int r = 0; r < 4; ++r) {                                        \
                float packed = __uint_as_float((__float_as_uint(acc[r]) & 0xFFFFFC00u) | codebits_); \
                best[tile*4 + r] = fmaxf(best[tile*4 + r], packed);              \
            }                                                                    \
        }                                                                        \
    } while (0)

    // Depth-2 software pipeline over 64 chunks of 16 codes; 4 named sets
    // (compile-time indexed, rule #20). Proven loop structure (r3).
    BSet s0 = loadB(cbF, cn2, 0, lane, n);
    BSet s1 = loadB(cbF, cn2, 1, lane, n);
#pragma unroll 1
    for (int ch = 0; ch < 64; ch += 4) {
        BSet t0 = loadB(cbF, cn2, (ch + 2) & 63, lane, n);
        COMPUTE(s0, ch);
        BSet t1 = loadB(cbF, cn2, (ch + 3) & 63, lane, n);
        COMPUTE(s1, ch + 1);
        s0 = loadB(cbF, cn2, (ch + 4) & 63, lane, n);
        COMPUTE(t0, ch + 2);
        s1 = loadB(cbF, cn2, (ch + 5) & 63, lane, n);
        COMPUTE(t1, ch + 3);
    }
#undef COMPUTE

    // Winner reduce (across the 16 code-lanes n per token row); ids ->
    // wave-local LDS; SSE from packed score (bit-identical r0/r2/r5).
    float sse_acc = 0.f;
#pragma unroll
    for (int s = 0; s < 8; ++s) {
        float bs = best[s];
#pragma unroll
        for (int m = 8; m >= 1; m >>= 1)
            bs = fmaxf(bs, __shfl_xor(bs, m, 64));
        u32 bits = __float_as_uint(bs);
        int id = (int)(bits & 0x3FFu);
        float sc = __uint_as_float(bits & 0xFFFFFC00u);
        float nrm = __shfl(pn[s >> 2], (q << 2) | (s & 3), 64);
        if (n == 0) {
            lidx[w*32 + (s >> 2)*16 + q*4 + (s & 3)] = id;
            sse_acc += fmaf(-2.f, sc, nrm);          // d = ||z||^2 - 2*score
        }
    }
    sse_acc += __shfl_xor(sse_acc, 16, 64);
    sse_acc += __shfl_xor(sse_acc, 32, 64);
    if (lane == 0) atomicAdd(&ssea[(blockIdx.x*4 + w) & 63], sse_acc);

    int myid = lidx[w*32 + (lane & 31)];             // wave-local LDS, no barrier
    if (lane < 32) gidx[wtok + lane] = myid;         // coalesced id publish

    // z_q write: wave's 32 tokens, readlane id -> coalesced row copies.
    const size_t obase = 1 + (size_t)wtok * DIM;
#pragma unroll
    for (int i = 0; i < 32; ++i) {
        int id = __shfl(myid, i, 64);                // compile-time lane -> v_readlane
        float qv = cb[(size_t)id * DIM + lane];
        out[obase + (size_t)i * DIM + lane] = qv;
    }
}

// Histogram from gidx (L2-hot) via per-block LDS counts, then spread global
// adds; last block computes entropy + loss. Proven r0-r3 epilogue mechanism.
__global__ __launch_bounds__(256) void hist_kernel(const int* __restrict__ gidx,
        unsigned* __restrict__ counts, const float* __restrict__ ssea,
        unsigned* __restrict__ done, float* __restrict__ out) {
    __shared__ unsigned hist[1024];
    __shared__ float fred[4];
    __shared__ u32 lastflag;
    const int t = threadIdx.x;
#pragma unroll
    for (int i = 0; i < 4; ++i) hist[t + 256*i] = 0u;
    __syncthreads();
    const int base = blockIdx.x * 4096;
#pragma unroll
    for (int i = 0; i < 16; ++i) {
        int id = gidx[base + i*256 + t];
        atomicAdd(&hist[id], 1u);
    }
    __syncthreads();
#pragma unroll
    for (int i = 0; i < 4; ++i) {
        unsigned v = hist[t + 256*i];
        if (v) atomicAdd(&counts[t + 256*i], v);
    }
    __threadfence();
    __syncthreads();
    if (t == 0) lastflag = (atomicAdd(done, 1u) == 31u) ? 1u : 0u;
    __syncthreads();
    if (lastflag) {
        float acc = 0.f;
#pragma unroll
        for (int i = 0; i < 4; ++i) {
            u32 cv = atomicAdd(&counts[t + 256*i], 0u);      // coherent read
            float p = (float)cv * (1.0f / 131072.0f);
            acc += p * logf(p + 1e-10f);
        }
#pragma unroll
        for (int off = 32; off; off >>= 1) acc += __shfl_down(acc, off, 64);
        if ((t & 63) == 0) fred[t >> 6] = acc;
        float sv = (t < 64) ? ssea[t] : 0.f;                 // prior-dispatch data
#pragma unroll
        for (int off = 32; off; off >>= 1) sv += __shfl_down(sv, off, 64);
        __syncthreads();
        if (t == 0) {
            float H = -((fred[0] + fred[1]) + (fred[2] + fred[3]));
            out[0] = 1.25f * sv * (1.0f / 8388608.0f);       // (1+BETA)*MSE
            out[8388609] = expf(H);
        }
    }
}

extern "C" void kernel_launch(void* const* d_in, const int* in_sizes, int n_in,
                              void* d_out, int out_size, void* d_ws, size_t ws_size,
                              hipStream_t stream) {
    const float* z  = (const float*)d_in[0];
    const float* cb = (const float*)d_in[1];
    float* out = (float*)d_out;
    char* ws = (char*)d_ws;
    float*     cn2    = (float*)(ws + WS_CN2);
    _Float16*  cbF    = (_Float16*)(ws + WS_CBF);
    int*       gidx   = (int*)(ws + WS_GIDX);
    unsigned*  counts = (unsigned*)(ws + WS_COUNTS);
    float*     ssea   = (float*)(ws + WS_SSEA);
    unsigned*  done   = (unsigned*)(ws + WS_DONE);

    prep_kernel<<<32, 256, 0, stream>>>(cb, cn2, cbF, counts, ssea, done);
    fused_kernel<<<N_TOK/128, 256, 0, stream>>>(z, cbF, cn2, cb, out, gidx, ssea);
    hist_kernel<<<32, 256, 0, stream>>>(gidx, counts, ssea, done, out);
}

// Round 9
// 121.128 us; speedup vs baseline: 1.1200x; 1.1200x over previous
//
#include <hip/hip_runtime.h>
#include <cfloat>
#include <cmath>

#define N_TOK (32*4096)                 // 131072 tokens
#define DIM   64
#define N_E   1024

typedef __attribute__((ext_vector_type(8))) _Float16 f16x8;
typedef __attribute__((ext_vector_type(4))) float    f32x4;
typedef unsigned int u32;

// ws layout (bytes)
#define WS_CN2    0u                    // 1024 f32 (-0.5*||e||^2)           (4 KB)
#define WS_CBF    4096u                 // fragment-ordered f16 (single plane, 128 KB)
#define WS_GIDX   135168u               // 131072 int winner ids             (512 KB)
#define WS_COUNTS 659456u               // 1024 u32
#define WS_SSEA   663552u               // 64 f32 partial SSE cells
#define WS_DONE   663808u               // 1 u32

// Codebook -> MFMA B-fragment order, f16 single plane:
//   cbF[ch*1024 + kf*512 + (q*16+n)*8 + j],  ch = 16-code chunk 0..63
__global__ __launch_bounds__(256) void prep_kernel(const float* __restrict__ cb,
        float* __restrict__ cn2, _Float16* __restrict__ cbF,
        unsigned* __restrict__ counts, float* __restrict__ ssea, unsigned* __restrict__ done) {
    const int t = threadIdx.x;
    const int k = blockIdx.x * 32 + (t >> 3);        // code 0..1023
    const int oct = t & 7;
    if (t < 32) counts[blockIdx.x * 32 + t] = 0u;
    if (blockIdx.x == 0 && t < 64) ssea[t] = 0.f;
    if (blockIdx.x == 0 && t == 0) *done = 0u;

    const float4 a = *(const float4*)(cb + (size_t)k * DIM + oct * 8);
    const float4 b = *(const float4*)(cb + (size_t)k * DIM + oct * 8 + 4);
    float v[8] = {a.x,a.y,a.z,a.w,b.x,b.y,b.z,b.w};
    f16x8 hv;
    float nrm = 0.f;
#pragma unroll
    for (int j = 0; j < 8; ++j) {
        float f = v[j];
        nrm = fmaf(f, f, nrm);
        hv[j] = (_Float16)f;
    }
    const int ch = k >> 4, n = k & 15;
    const int kf = oct >> 2, q = oct & 3;
    *(f16x8*)(cbF + (size_t)(ch * 1024 + kf * 512 + q * 128 + n * 8)) = hv;
    nrm += __shfl_xor(nrm, 1, 64);
    nrm += __shfl_xor(nrm, 2, 64);
    nrm += __shfl_xor(nrm, 4, 64);
    if (oct == 0) cn2[k] = -0.5f * nrm;              // exact fp32 -||e||^2/2
}

// Round-14 fused: 64 tok/wave, 512 blocks (proven best shape), f16 depth-2
// 4-BSet register streaming — with sched_barrier(0) FENCES pinning each
// load-issue block ABOVE the following COMPUTE. Diagnosis (r8): VGPR=52
// proves the compiler sank the prefetch loads to their use point, compiling
// the pipeline away — every chunk then ate a full exposed L2 round-trip
// (~400cyc), matching the measured 543 cyc/chunk/SIMD. Fences forbid the
// sink; marker of success: VGPR ~100-115. Packed-score SSE epilogue
// (bit-identical absmax, r5/r6/r8), gidx publish + separate hist dispatch.
struct BSet { f16x8 h0, h1; float cn; };

__device__ __forceinline__ BSet loadB(const _Float16* __restrict__ cbF,
                                      const float* __restrict__ cn2,
                                      int ch, int lane, int n) {
    const _Float16* p = cbF + (size_t)((ch << 10) + (lane << 3));
    BSet s;
    s.h0 = *(const f16x8*)(p);
    s.h1 = *(const f16x8*)(p + 512);
    s.cn = cn2[(ch << 4) | n];
    return s;
}

__global__ __launch_bounds__(256, 2) void fused_kernel(const float* __restrict__ z,
        const _Float16* __restrict__ cbF, const float* __restrict__ cn2,
        const float* __restrict__ cb, float* __restrict__ out,
        int* __restrict__ gidx, float* __restrict__ ssea) {
    __shared__ int lidx[256];                        // wave-local id bounce only
    const int t    = threadIdx.x;
    const int lane = t & 63;
    const int w    = t >> 6;
    const int n    = lane & 15;                      // MFMA col / code-in-chunk
    const int q    = lane >> 4;                      // k-octet selector
    const int wtok = blockIdx.x * 256 + w * 64;

    // A fragments (64 tokens/wave as 4 tiles x 2 K-halves), f16 in regs + norms.
    f16x8 ah[4][2];
    float pn[4];
    const float4* z4 = (const float4*)z;
#pragma unroll
    for (int tile = 0; tile < 4; ++tile) {
        int tok = wtok + tile*16 + n;
        float nrm = 0.f;
#pragma unroll
        for (int kf = 0; kf < 2; ++kf) {
            float4 p0 = z4[(size_t)tok*16 + kf*8 + q*2];
            float4 p1 = z4[(size_t)tok*16 + kf*8 + q*2 + 1];
            float v[8] = {p0.x,p0.y,p0.z,p0.w,p1.x,p1.y,p1.z,p1.w};
            f16x8 hv;
#pragma unroll
            for (int j = 0; j < 8; ++j) {
                float f = v[j];
                nrm = fmaf(f, f, nrm);
                hv[j] = (_Float16)f;
            }
            ah[tile][kf] = hv;
        }
        nrm += __shfl_xor(nrm, 16, 64);
        nrm += __shfl_xor(nrm, 32, 64);
        pn[tile] = nrm;
    }

    float best[16];
#pragma unroll
    for (int s = 0; s < 16; ++s) best[s] = -3.4e38f;

#define COMPUTE(S, CH) do {                                                       \
        const float cnv_ = (S).cn;                                               \
        const u32 codebits_ = (u32)(((CH) << 4) | n);                            \
        _Pragma("unroll")                                                        \
        for (int tile = 0; tile < 4; ++tile) {                                   \
            f32x4 acc = {cnv_, cnv_, cnv_, cnv_};                                \
            acc = __builtin_amdgcn_mfma_f32_16x16x32_f16(ah[tile][0], (S).h0, acc, 0, 0, 0); \
            acc = __builtin_amdgcn_mfma_f32_16x16x32_f16(ah[tile][1], (S).h1, acc, 0, 0, 0); \
            _Pragma("unroll")                                                    \
            for (int r = 0; r < 4; ++r) {                                        \
                float packed = __uint_as_float((__float_as_uint(acc[r]) & 0xFFFFFC00u) | codebits_); \
                best[tile*4 + r] = fmaxf(best[tile*4 + r], packed);              \
            }                                                                    \
        }                                                                        \
    } while (0)

    // Depth-2 pipeline over 64 chunks of 16 codes; 4 named sets. Each
    // sched_barrier(0) pins the just-issued loads ABOVE the next COMPUTE so
    // the scheduler cannot sink them to their use (r8 failure mode).
    BSet s0 = loadB(cbF, cn2, 0, lane, n);
    BSet s1 = loadB(cbF, cn2, 1, lane, n);
#pragma unroll 1
    for (int ch = 0; ch < 64; ch += 4) {
        BSet t0 = loadB(cbF, cn2, (ch + 2) & 63, lane, n);
        __builtin_amdgcn_sched_barrier(0);
        COMPUTE(s0, ch);
        BSet t1 = loadB(cbF, cn2, (ch + 3) & 63, lane, n);
        __builtin_amdgcn_sched_barrier(0);
        COMPUTE(s1, ch + 1);
        s0 = loadB(cbF, cn2, (ch + 4) & 63, lane, n);
        __builtin_amdgcn_sched_barrier(0);
        COMPUTE(t0, ch + 2);
        s1 = loadB(cbF, cn2, (ch + 5) & 63, lane, n);
        __builtin_amdgcn_sched_barrier(0);
        COMPUTE(t1, ch + 3);
    }
#undef COMPUTE

    // Winner reduce; ids -> wave-local LDS; SSE from packed score.
    float sse_acc = 0.f;
#pragma unroll
    for (int s = 0; s < 16; ++s) {
        float bs = best[s];
#pragma unroll
        for (int m = 8; m >= 1; m >>= 1)
            bs = fmaxf(bs, __shfl_xor(bs, m, 64));
        u32 bits = __float_as_uint(bs);
        int id = (int)(bits & 0x3FFu);
        float sc = __uint_as_float(bits & 0xFFFFFC00u);
        float nrm = __shfl(pn[s >> 2], (q << 2) | (s & 3), 64);
        if (n == 0) {
            lidx[w*64 + (s >> 2)*16 + q*4 + (s & 3)] = id;
            sse_acc += fmaf(-2.f, sc, nrm);          // d = ||z||^2 - 2*score
        }
    }
    sse_acc += __shfl_xor(sse_acc, 16, 64);
    sse_acc += __shfl_xor(sse_acc, 32, 64);
    if (lane == 0) atomicAdd(&ssea[(blockIdx.x*4 + w) & 63], sse_acc);

    int myid = lidx[w*64 + lane];                    // wave-local LDS, no barrier needed
    gidx[wtok + lane] = myid;                        // coalesced id publish

    // z_q write: wave's 64 tokens, readlane id -> coalesced row copies.
    const size_t obase = 1 + (size_t)wtok * DIM;
#pragma unroll
    for (int i = 0; i < 64; ++i) {
        int id = __shfl(myid, i, 64);                // compile-time lane -> v_readlane
        float qv = cb[(size_t)id * DIM + lane];
        out[obase + (size_t)i * DIM + lane] = qv;
    }
}

// Histogram from gidx (L2-hot) via per-block LDS counts, then spread global
// adds; last block computes entropy + loss. Proven r0-r3 epilogue mechanism.
__global__ __launch_bounds__(256) void hist_kernel(const int* __restrict__ gidx,
        unsigned* __restrict__ counts, const float* __restrict__ ssea,
        unsigned* __restrict__ done, float* __restrict__ out) {
    __shared__ unsigned hist[1024];
    __shared__ float fred[4];
    __shared__ u32 lastflag;
    const int t = threadIdx.x;
#pragma unroll
    for (int i = 0; i < 4; ++i) hist[t + 256*i] = 0u;
    __syncthreads();
    const int base = blockIdx.x * 4096;
#pragma unroll
    for (int i = 0; i < 16; ++i) {
        int id = gidx[base + i*256 + t];
        atomicAdd(&hist[id], 1u);
    }
    __syncthreads();
#pragma unroll
    for (int i = 0; i < 4; ++i) {
        unsigned v = hist[t + 256*i];
        if (v) atomicAdd(&counts[t + 256*i], v);
    }
    __threadfence();
    __syncthreads();
    if (t == 0) lastflag = (atomicAdd(done, 1u) == 31u) ? 1u : 0u;
    __syncthreads();
    if (lastflag) {
        float acc = 0.f;
#pragma unroll
        for (int i = 0; i < 4; ++i) {
            u32 cv = atomicAdd(&counts[t + 256*i], 0u);      // coherent read
            float p = (float)cv * (1.0f / 131072.0f);
            acc += p * logf(p + 1e-10f);
        }
#pragma unroll
        for (int off = 32; off; off >>= 1) acc += __shfl_down(acc, off, 64);
        if ((t & 63) == 0) fred[t >> 6] = acc;
        float sv = (t < 64) ? ssea[t] : 0.f;                 // prior-dispatch data
#pragma unroll
        for (int off = 32; off; off >>= 1) sv += __shfl_down(sv, off, 64);
        __syncthreads();
        if (t == 0) {
            float H = -((fred[0] + fred[1]) + (fred[2] + fred[3]));
            out[0] = 1.25f * sv * (1.0f / 8388608.0f);       // (1+BETA)*MSE
            out[8388609] = expf(H);
        }
    }
}

extern "C" void kernel_launch(void* const* d_in, const int* in_sizes, int n_in,
                              void* d_out, int out_size, void* d_ws, size_t ws_size,
                              hipStream_t stream) {
    const float* z  = (const float*)d_in[0];
    const float* cb = (const float*)d_in[1];
    float* out = (float*)d_out;
    char* ws = (char*)d_ws;
    float*     cn2    = (float*)(ws + WS_CN2);
    _Float16*  cbF    = (_Float16*)(ws + WS_CBF);
    int*       gidx   = (int*)(ws + WS_GIDX);
    unsigned*  counts = (unsigned*)(ws + WS_COUNTS);
    float*     ssea   = (float*)(ws + WS_SSEA);
    unsigned*  done   = (unsigned*)(ws + WS_DONE);

    prep_kernel<<<32, 256, 0, stream>>>(cb, cn2, cbF, counts, ssea, done);
    fused_kernel<<<N_TOK/256, 256, 0, stream>>>(z, cbF, cn2, cb, out, gidx, ssea);
    hist_kernel<<<32, 256, 0, stream>>>(gidx, counts, ssea, done, out);
}

// Round 10
// 119.459 us; speedup vs baseline: 1.1356x; 1.0140x over previous
//
#include <hip/hip_runtime.h>
#include <cfloat>
#include <cmath>

#define N_TOK (32*4096)                 // 131072 tokens
#define DIM   64
#define N_E   1024

typedef __attribute__((ext_vector_type(8))) _Float16 f16x8;
typedef __attribute__((ext_vector_type(4))) float    f32x4;
typedef unsigned int u32;

// ws layout (bytes)
#define WS_CN2    0u                    // 1024 f32 (-0.5*||e||^2)           (4 KB)
#define WS_CBF    4096u                 // fragment-ordered f16 (single plane, 128 KB)
#define WS_GIDX   135168u               // 131072 int winner ids             (512 KB)
#define WS_COUNTS 659456u               // 1024 u32
#define WS_SSEA   663552u               // 64 f32 partial SSE cells
#define WS_DONE   663808u               // 1 u32

// async global->LDS, 16 B per lane; LDS dest must be wave-uniform base + lane*16
__device__ __forceinline__ void async_cp16(const void* g, void* l) {
    __builtin_amdgcn_global_load_lds((const __attribute__((address_space(1))) u32*)g,
                                     (__attribute__((address_space(3))) u32*)l, 16, 0, 0);
}

// Codebook -> MFMA B-fragment order, f16 single plane:
//   cbF[ch*1024 + kf*512 + (q*16+n)*8 + j],  ch = 16-code chunk 0..63
__global__ __launch_bounds__(256) void prep_kernel(const float* __restrict__ cb,
        float* __restrict__ cn2, _Float16* __restrict__ cbF,
        unsigned* __restrict__ counts, float* __restrict__ ssea, unsigned* __restrict__ done) {
    const int t = threadIdx.x;
    const int k = blockIdx.x * 32 + (t >> 3);        // code 0..1023
    const int oct = t & 7;
    if (t < 32) counts[blockIdx.x * 32 + t] = 0u;
    if (blockIdx.x == 0 && t < 64) ssea[t] = 0.f;
    if (blockIdx.x == 0 && t == 0) *done = 0u;

    const float4 a = *(const float4*)(cb + (size_t)k * DIM + oct * 8);
    const float4 b = *(const float4*)(cb + (size_t)k * DIM + oct * 8 + 4);
    float v[8] = {a.x,a.y,a.z,a.w,b.x,b.y,b.z,b.w};
    f16x8 hv;
    float nrm = 0.f;
#pragma unroll
    for (int j = 0; j < 8; ++j) {
        float f = v[j];
        nrm = fmaf(f, f, nrm);
        hv[j] = (_Float16)f;
    }
    const int ch = k >> 4, n = k & 15;
    const int kf = oct >> 2, q = oct & 3;
    *(f16x8*)(cbF + (size_t)(ch * 1024 + kf * 512 + q * 128 + n * 8)) = hv;
    nrm += __shfl_xor(nrm, 1, 64);
    nrm += __shfl_xor(nrm, 2, 64);
    nrm += __shfl_xor(nrm, 4, 64);
    if (oct == 0) cn2[k] = -0.5f * nrm;              // exact fp32 -||e||^2/2
}

// Round-15 fused: ENTIRE 128 KB f16 codebook resident in LDS (one-time
// global_load_lds stage, ONE barrier), then a barrier-free 64-chunk loop
// reading B-fragments via ds_read_b128 (~120cyc fixed latency; compiler's
// fine lgkmcnt scheduling is proven near-optimal) instead of L2 round-trips
// (~300cyc, vmcnt-fragile — r8/r9 showed the scheduler defeats register
// prefetch pipelines). 512-thread blocks (8 waves x 64 tokens/wave, proven
// best shape), 256 blocks = 1 block/CU (LDS-capped: 134 KB).
__global__ __launch_bounds__(512, 2) void fused_kernel(const float* __restrict__ z,
        const _Float16* __restrict__ cbF, const float* __restrict__ cn2,
        const float* __restrict__ cb, float* __restrict__ out,
        int* __restrict__ gidx, float* __restrict__ ssea) {
    __shared__ __align__(16) _Float16 lbuf[65536];   // 128 KB codebook, fragment order
    __shared__ __align__(16) float lcn[1024];        // 4 KB -0.5||e||^2
    __shared__ int lidx[512];                        // wave-local id bounce
    const int t    = threadIdx.x;
    const int lane = t & 63;
    const int w    = t >> 6;                         // wave 0..7
    const int n    = lane & 15;                      // MFMA col / code-in-chunk
    const int q    = lane >> 4;                      // k-octet selector
    const int wtok = blockIdx.x * 512 + w * 64;

    // Stage codebook + cn2 into LDS (async, overlaps the A-fragment build).
#pragma unroll
    for (int i = 0; i < 16; ++i)
        async_cp16((const char*)cbF + i*8192 + t*16, (char*)lbuf + i*8192 + t*16);
    if (t < 256)
        async_cp16((const char*)cn2 + t*16, (char*)lcn + t*16);

    // A fragments (64 tokens/wave as 4 tiles x 2 K-halves), f16 in regs + norms.
    f16x8 ah[4][2];
    float pn[4];
    const float4* z4 = (const float4*)z;
#pragma unroll
    for (int tile = 0; tile < 4; ++tile) {
        int tok = wtok + tile*16 + n;
        float nrm = 0.f;
#pragma unroll
        for (int kf = 0; kf < 2; ++kf) {
            float4 p0 = z4[(size_t)tok*16 + kf*8 + q*2];
            float4 p1 = z4[(size_t)tok*16 + kf*8 + q*2 + 1];
            float v[8] = {p0.x,p0.y,p0.z,p0.w,p1.x,p1.y,p1.z,p1.w};
            f16x8 hv;
#pragma unroll
            for (int j = 0; j < 8; ++j) {
                float f = v[j];
                nrm = fmaf(f, f, nrm);
                hv[j] = (_Float16)f;
            }
            ah[tile][kf] = hv;
        }
        nrm += __shfl_xor(nrm, 16, 64);
        nrm += __shfl_xor(nrm, 32, 64);
        pn[tile] = nrm;
    }

    float best[16];
#pragma unroll
    for (int s = 0; s < 16; ++s) best[s] = -3.4e38f;

    __syncthreads();                                 // staging complete (drains vmcnt)

    // Barrier-free main loop: B-fragments from LDS. Unroll 4 lets the
    // compiler software-pipeline ds_reads across chunks with counted lgkmcnt.
#pragma unroll 4
    for (int ch = 0; ch < 64; ++ch) {
        const _Float16* p = lbuf + (ch << 10) + (lane << 3);
        f16x8 bh0 = *(const f16x8*)(p);
        f16x8 bh1 = *(const f16x8*)(p + 512);
        const float cnv = lcn[(ch << 4) | n];
        const u32 codebits = (u32)((ch << 4) | n);
#pragma unroll
        for (int tile = 0; tile < 4; ++tile) {
            f32x4 acc = {cnv, cnv, cnv, cnv};
            acc = __builtin_amdgcn_mfma_f32_16x16x32_f16(ah[tile][0], bh0, acc, 0, 0, 0);
            acc = __builtin_amdgcn_mfma_f32_16x16x32_f16(ah[tile][1], bh1, acc, 0, 0, 0);
#pragma unroll
            for (int r = 0; r < 4; ++r) {
                float packed = __uint_as_float((__float_as_uint(acc[r]) & 0xFFFFFC00u) | codebits);
                best[tile*4 + r] = fmaxf(best[tile*4 + r], packed);
            }
        }
    }

    // Winner reduce; ids -> wave-local LDS; SSE from packed score
    // (bit-identical absmax r5/r6/r8/r9).
    float sse_acc = 0.f;
#pragma unroll
    for (int s = 0; s < 16; ++s) {
        float bs = best[s];
#pragma unroll
        for (int m = 8; m >= 1; m >>= 1)
            bs = fmaxf(bs, __shfl_xor(bs, m, 64));
        u32 bits = __float_as_uint(bs);
        int id = (int)(bits & 0x3FFu);
        float sc = __uint_as_float(bits & 0xFFFFFC00u);
        float nrm = __shfl(pn[s >> 2], (q << 2) | (s & 3), 64);
        if (n == 0) {
            lidx[w*64 + (s >> 2)*16 + q*4 + (s & 3)] = id;
            sse_acc += fmaf(-2.f, sc, nrm);          // d = ||z||^2 - 2*score
        }
    }
    sse_acc += __shfl_xor(sse_acc, 16, 64);
    sse_acc += __shfl_xor(sse_acc, 32, 64);
    if (lane == 0) atomicAdd(&ssea[(blockIdx.x*8 + w) & 63], sse_acc);

    int myid = lidx[w*64 + lane];                    // wave-local LDS, no barrier needed
    gidx[wtok + lane] = myid;                        // coalesced id publish

    // z_q write: wave's 64 tokens, readlane id -> coalesced row copies.
    const size_t obase = 1 + (size_t)wtok * DIM;
#pragma unroll
    for (int i = 0; i < 64; ++i) {
        int id = __shfl(myid, i, 64);                // compile-time lane -> v_readlane
        float qv = cb[(size_t)id * DIM + lane];
        out[obase + (size_t)i * DIM + lane] = qv;
    }
}

// Histogram from gidx (L2-hot) via per-block LDS counts, then spread global
// adds; last block computes entropy + loss. Proven r0-r3 epilogue mechanism.
__global__ __launch_bounds__(256) void hist_kernel(const int* __restrict__ gidx,
        unsigned* __restrict__ counts, const float* __restrict__ ssea,
        unsigned* __restrict__ done, float* __restrict__ out) {
    __shared__ unsigned hist[1024];
    __shared__ float fred[4];
    __shared__ u32 lastflag;
    const int t = threadIdx.x;
#pragma unroll
    for (int i = 0; i < 4; ++i) hist[t + 256*i] = 0u;
    __syncthreads();
    const int base = blockIdx.x * 4096;
#pragma unroll
    for (int i = 0; i < 16; ++i) {
        int id = gidx[base + i*256 + t];
        atomicAdd(&hist[id], 1u);
    }
    __syncthreads();
#pragma unroll
    for (int i = 0; i < 4; ++i) {
        unsigned v = hist[t + 256*i];
        if (v) atomicAdd(&counts[t + 256*i], v);
    }
    __threadfence();
    __syncthreads();
    if (t == 0) lastflag = (atomicAdd(done, 1u) == 31u) ? 1u : 0u;
    __syncthreads();
    if (lastflag) {
        float acc = 0.f;
#pragma unroll
        for (int i = 0; i < 4; ++i) {
            u32 cv = atomicAdd(&counts[t + 256*i], 0u);      // coherent read
            float p = (float)cv * (1.0f / 131072.0f);
            acc += p * logf(p + 1e-10f);
        }
#pragma unroll
        for (int off = 32; off; off >>= 1) acc += __shfl_down(acc, off, 64);
        if ((t & 63) == 0) fred[t >> 6] = acc;
        float sv = (t < 64) ? ssea[t] : 0.f;                 // prior-dispatch data
#pragma unroll
        for (int off = 32; off; off >>= 1) sv += __shfl_down(sv, off, 64);
        __syncthreads();
        if (t == 0) {
            float H = -((fred[0] + fred[1]) + (fred[2] + fred[3]));
            out[0] = 1.25f * sv * (1.0f / 8388608.0f);       // (1+BETA)*MSE
            out[8388609] = expf(H);
        }
    }
}

extern "C" void kernel_launch(void* const* d_in, const int* in_sizes, int n_in,
                              void* d_out, int out_size, void* d_ws, size_t ws_size,
                              hipStream_t stream) {
    const float* z  = (const float*)d_in[0];
    const float* cb = (const float*)d_in[1];
    float* out = (float*)d_out;
    char* ws = (char*)d_ws;
    float*     cn2    = (float*)(ws + WS_CN2);
    _Float16*  cbF    = (_Float16*)(ws + WS_CBF);
    int*       gidx   = (int*)(ws + WS_GIDX);
    unsigned*  counts = (unsigned*)(ws + WS_COUNTS);
    float*     ssea   = (float*)(ws + WS_SSEA);
    unsigned*  done   = (unsigned*)(ws + WS_DONE);

    prep_kernel<<<32, 256, 0, stream>>>(cb, cn2, cbF, counts, ssea, done);
    fused_kernel<<<N_TOK/512, 512, 0, stream>>>(z, cbF, cn2, cb, out, gidx, ssea);
    hist_kernel<<<32, 256, 0, stream>>>(gidx, counts, ssea, done, out);
}